// Round 17
// baseline (29.945 us; speedup 1.0000x reference)
//
#include <hip/hip_runtime.h>
#include <hip/hip_bf16.h>
#include <math.h>

// ---------------------------------------------------------------------------
// MFMA-based fused GCN-attention (3 kernels) — r14 K1 structure, NKQ=16 to
// double resident waves/SIMD (isolated occupancy test; r11/r15 never
// isolated this: they bundled PSTR=24 / 2-q-tile VGPR pressure):
//  K0 prep_frags: bf16 MFMA fragments (hi/lo split), per 32-key tile
//     [Ah | Al | Bx0 | Bx1] (1 KB each), linear stream (1.57 MB).
//  K1 attn_mfma: per wave: 32-q tile, 256-key slice (8 tiles). Frags
//     global->VGPR ping-pong, zero LDS, zero barriers. Per tile:
//       S^T = mfma(Kh,Qh)+mfma(Kh,Ql)+mfma(Kl,Qh)   (split precision)
//       p = exp2(S*LOG2E-SHIFT2) -> fast pack -> permlane32_swap -> P
//       Cv += mfma(P0,Bx0)+mfma(P1,Bx1)   (V_hi | V_lo | l in one acc)
//     Store: v = hi + __shfl(lo) in-register, 11 columns (0-9 v, 10 l).
//  K2 finalize2 (r15-proven 16-slice): thread = (qLocal, n, slice); 16
//     slices in 16 consecutive lanes -> 4-step __shfl_xor reduce; BN+adj;
//     1 barrier; W-matmul + pool.
// Fallback (small ws): round-7 scalar path (proven correct).
// ---------------------------------------------------------------------------

constexpr int BTOT = 4096;
constexpr int NN   = 3;
constexpr int DIM  = 10;
constexpr int ROW  = 30;          // floats per batch row
constexpr int NKQ  = 16;          // key slices (256 keys each)
constexpr int NTILE= 128;         // 32-key tiles per node
constexpr int NT   = NTILE / NKQ; // 8 tiles per wave slice
constexpr int PSTR = 12;          // pws row stride (floats)
constexpr int QB2  = 8;           // queries per finalize2 block
constexpr float LOG2E  = 1.4426950408889634f;
constexpr float SHIFT2 = 20.0f * LOG2E;
constexpr float EPS = 1e-5f;

#if __has_builtin(__builtin_amdgcn_exp2f)
#define EXP2(x) __builtin_amdgcn_exp2f(x)
#else
#define EXP2(x) exp2f(x)
#endif

typedef __attribute__((ext_vector_type(8)))  short bf16x8;
typedef __attribute__((ext_vector_type(16))) float f32x16;

static __device__ __forceinline__ unsigned short bfbits(float x){
    __hip_bfloat16 h = __float2bfloat16(x);
    unsigned short u; __builtin_memcpy(&u, &h, 2); return u;
}
static __device__ __forceinline__ float bff(float x){
    return __bfloat162float(__float2bfloat16(x));
}
static __device__ __forceinline__ unsigned packbf(float lo, float hi){
    return ((unsigned)bfbits(hi) << 16) | bfbits(lo);   // RNE (prep only)
}
// fast pack: round-half-up via +0x8000, merge with one v_perm_b32 (proven r11/r13)
static __device__ __forceinline__ unsigned packbf_fast(float lo, float hi){
    unsigned ulo, uhi;
    __builtin_memcpy(&ulo, &lo, 4);
    __builtin_memcpy(&uhi, &hi, 4);
    ulo += 0x8000u; uhi += 0x8000u;
#if __has_builtin(__builtin_amdgcn_perm)
    return __builtin_amdgcn_perm(uhi, ulo, 0x07060302u);
#else
    return (uhi & 0xFFFF0000u) | (ulo >> 16);
#endif
}

// ------------------------------- K0: prep ----------------------------------
__global__ __launch_bounds__(256) void prep_frags(const float* __restrict__ x,
                                                  unsigned* __restrict__ fr)
{
    const int n = blockIdx.x >> 7;      // node
    const int t = blockIdx.x & 127;     // 32-key tile
    const int f = threadIdx.x >> 6;     // frag: 0=Ah 1=Al 2=Bx0 3=Bx1
    const int l = threadIdx.x & 63;     // frag lane
    const int h = l >> 5;
    unsigned o[4];
    if (f < 2) {
        // A-frag: lane l holds A[key = 32t+(l&31)][feat = 8h+b], b=0..7
        const float* xp = x + (size_t)(32*t + (l & 31)) * ROW + n * DIM;
        #pragma unroll
        for (int w = 0; w < 4; ++w) {
            const int f0 = 8*h + 2*w;
            float x0 = (f0     < DIM) ? xp[f0]     : 0.f;
            float x1 = (f0 + 1 < DIM) ? xp[f0 + 1] : 0.f;
            o[w] = (f == 0) ? packbf(x0, x1)
                            : packbf(x0 - bff(x0), x1 - bff(x1));
        }
    } else {
        // Bx-frag chunk c: lane l holds B[kk = 8h+b][col = l&31],
        // key = 32t+16c+kk; col: 0-9 x_hi, 10-19 x_lo, 20 ones, 21-31 zero
        const int c  = f - 2;
        const int dp = l & 31;
        #pragma unroll
        for (int w = 0; w < 4; ++w) {
            float v[2];
            #pragma unroll
            for (int e = 0; e < 2; ++e) {
                const int r = 32*t + 16*c + 8*h + 2*w + e;
                float val;
                if (dp < DIM) {
                    val = bff(x[(size_t)r*ROW + n*DIM + dp]);
                } else if (dp < 2*DIM) {
                    float xx = x[(size_t)r*ROW + n*DIM + dp - DIM];
                    val = xx - bff(xx);
                } else {
                    val = (dp == 2*DIM) ? 1.0f : 0.0f;
                }
                v[e] = val;
            }
            o[w] = packbf(v[0], v[1]);
        }
    }
    unsigned* dst = fr + ((((size_t)n*NTILE + t)*4 + f) << 8) + l*4;
    *(uint4*)dst = make_uint4(o[0], o[1], o[2], o[3]);
}

// ------------------------------- K1: attention -----------------------------
union FU { uint4 q; bf16x8 v; };
struct Tile { FU fAh, fAl, fB0, fB1; };

__device__ __forceinline__ void loadTile(const unsigned* __restrict__ fr,
                                         int n, int t, int l, Tile& T)
{
    const unsigned* p = fr + ((((size_t)n*NTILE + t)*4) << 8) + l*4;
    T.fAh.q = *(const uint4*)(p);
    T.fAl.q = *(const uint4*)(p + 256);
    T.fB0.q = *(const uint4*)(p + 512);
    T.fB1.q = *(const uint4*)(p + 768);
}

__device__ __forceinline__ void computeTile(const Tile& T,
                                            const FU& quh, const FU& qul,
                                            f32x16& Cv)
{
    // S^T (32k x 32q), split precision: Kh*Qh + Kh*Ql + Kl*Qh
    f32x16 S;
    #pragma unroll
    for (int i = 0; i < 16; ++i) S[i] = 0.f;
    S = __builtin_amdgcn_mfma_f32_32x32x16_bf16(T.fAh.v, quh.v, S, 0, 0, 0);
    S = __builtin_amdgcn_mfma_f32_32x32x16_bf16(T.fAh.v, qul.v, S, 0, 0, 0);
    S = __builtin_amdgcn_mfma_f32_32x32x16_bf16(T.fAl.v, quh.v, S, 0, 0, 0);

    // p = exp2(LOG2E*S - SHIFT2); lane holds k = (reg&3)+8*(reg>>2)+4h
    float p[16];
    #pragma unroll
    for (int i = 0; i < 16; ++i) p[i] = EXP2(fmaf(S[i], LOG2E, -SHIFT2));

    // pack pairs then swap across lane<32/lane>=32 halves
    unsigned W0[2] = {packbf_fast(p[0],  p[1]),  packbf_fast(p[2],  p[3])};
    unsigned W1[2] = {packbf_fast(p[4],  p[5]),  packbf_fast(p[6],  p[7])};
    unsigned W2[2] = {packbf_fast(p[8],  p[9]),  packbf_fast(p[10], p[11])};
    unsigned W3[2] = {packbf_fast(p[12], p[13]), packbf_fast(p[14], p[15])};
    asm("v_permlane32_swap_b32 %0, %1" : "+v"(W0[0]), "+v"(W1[0]));
    asm("v_permlane32_swap_b32 %0, %1" : "+v"(W0[1]), "+v"(W1[1]));
    asm("v_permlane32_swap_b32 %0, %1" : "+v"(W2[0]), "+v"(W3[0]));
    asm("v_permlane32_swap_b32 %0, %1" : "+v"(W2[1]), "+v"(W3[1]));

    FU P0, P1;
    P0.q = make_uint4(W0[0], W0[1], W1[0], W1[1]);  // keys 0..15 of tile
    P1.q = make_uint4(W2[0], W2[1], W3[0], W3[1]);  // keys 16..31

    Cv = __builtin_amdgcn_mfma_f32_32x32x16_bf16(P0.v, T.fB0.v, Cv, 0, 0, 0);
    Cv = __builtin_amdgcn_mfma_f32_32x32x16_bf16(P1.v, T.fB1.v, Cv, 0, 0, 0);
}

__global__ __launch_bounds__(256, 3) void attn_mfma(
    const unsigned* __restrict__ fr, float* __restrict__ pws)
{
    const int bx  = blockIdx.x;
    const int qg  = bx / (NN*NKQ);
    const int rem = bx % (NN*NKQ);
    const int n   = rem / NKQ;
    const int kq  = rem % NKQ;
    const int w   = threadIdx.x >> 6;
    const int l   = threadIdx.x & 63;
    const int qt  = qg*4 + w;           // this wave's 32-q tile

    // Q-side frags (hi/lo) = Ah/Al of tile qt (identical byte layout)
    FU quh, qul;
    {
        const unsigned* p = fr + ((((size_t)n*NTILE + qt)*4) << 8) + l*4;
        quh.q = *(const uint4*)p;
        qul.q = *(const uint4*)(p + 256);
    }

    f32x16 Cv;
    #pragma unroll
    for (int i = 0; i < 16; ++i) Cv[i] = 0.f;

    const int t0 = kq * NT;

    // ping-pong: zero LDS, zero barriers, loads overlap compute
    Tile TA, TB;
    loadTile(fr, n, t0, l, TA);
    #pragma unroll
    for (int it = 0; it < NT/2 - 1; ++it) {
        loadTile(fr, n, t0 + 2*it + 1, l, TB);
        computeTile(TA, quh, qul, Cv);
        loadTile(fr, n, t0 + 2*it + 2, l, TA);
        computeTile(TB, quh, qul, Cv);
    }
    loadTile(fr, n, t0 + NT - 1, l, TB);
    computeTile(TA, quh, qul, Cv);
    computeTile(TB, quh, qul, Cv);

    // in-register hi+lo combine: lane dp (<10) adds lane dp+10's Cv.
    float add10[16];
    #pragma unroll
    for (int r = 0; r < 16; ++r) add10[r] = __shfl(Cv[r], l + 10);

    // store 11 columns: 0-9 = v (hi+lo), 10 = l-sum
    const int dp = l & 31;
    const int h  = l >> 5;
    if (dp < DIM || dp == 2*DIM) {
        const int col = (dp < DIM) ? dp : DIM;
        float* base = pws + (((size_t)(n*NKQ + kq)*BTOT) + qt*32) * PSTR + col;
        #pragma unroll
        for (int r = 0; r < 16; ++r) {
            const int q = (r & 3) + 8*(r >> 2) + 4*h;
            float v = Cv[r];
            if (dp < DIM) v += add10[r];
            base[q * PSTR] = v;
        }
    }
}

// ------------------------------- K2: finalize2 -----------------------------
// thread = (qLocal, n, slice): tid = (qLocal*NN + n)*16 + slice.
// 16 slices are 16 consecutive lanes (aligned) -> 4-step shfl_xor reduce.
__global__ __launch_bounds__(QB2 * NN * 16) void finalize2(
    const float* __restrict__ pws, const float* __restrict__ A,
    const float* __restrict__ W, const float* __restrict__ bn_g,
    const float* __restrict__ bn_b, const float* __restrict__ bn_m,
    const float* __restrict__ bn_v, float* __restrict__ out)
{
    __shared__ float ubuf[QB2][NN][11];   // 1.1 KB
    const int tid   = threadIdx.x;        // 384
    const int slice = tid & 15;
    const int row   = tid >> 4;           // 0..23
    const int n     = row % NN;
    const int qL    = row / NN;
    const int q     = blockIdx.x * QB2 + qL;

    // read this slice's 11 partials
    const float* p = pws + ((size_t)((n*NKQ + slice)*BTOT) + q) * PSTR;
    float4 v0 = *(const float4*)(p);
    float4 v1 = *(const float4*)(p + 4);
    float2 v2 = *(const float2*)(p + 8);
    float  lv = p[10];
    float acc[11] = {v0.x, v0.y, v0.z, v0.w, v1.x, v1.y, v1.z, v1.w,
                     v2.x, v2.y, lv};

    // butterfly reduce over the 16 slices (4 steps, in-wave)
    #pragma unroll
    for (int m = 1; m < 16; m <<= 1) {
        #pragma unroll
        for (int i = 0; i < 11; ++i) acc[i] += __shfl_xor(acc[i], m);
    }

    if (slice == 0) {
        const float inv = 1.0f / acc[10];
        const float sc  = bn_g[n] * rsqrtf(bn_v[n] + EPS);
        const float sh  = bn_b[n] - bn_m[n] * sc;
        const float cw  = 0.125f * (((n == 0) ? 0.f : 1.f) + A[n] +
                                    ((n == 1) ? 0.f : 1.f) + A[NN + n]);
        #pragma unroll
        for (int d = 0; d < DIM; ++d)
            ubuf[qL][n][d] = cw * (acc[d] * inv * sc + sh);
    }
    __syncthreads();

    // QB2*DIM = 80 threads: out[q][dout] = sum_e (sum_n u) * W[e][dout]
    if (tid < QB2 * DIM) {
        const int qL2  = tid / DIM;
        const int dout = tid - qL2 * DIM;
        float o = 0.f;
        #pragma unroll
        for (int e = 0; e < DIM; ++e) {
            float u = ubuf[qL2][0][e] + ubuf[qL2][1][e] + ubuf[qL2][2][e];
            o = fmaf(u, W[e*DIM + dout], o);
        }
        out[(blockIdx.x * QB2 + qL2) * DIM + dout] = o;
    }
}

// --------------------------- fallback (round-7, proven) --------------------
constexpr int QPB = 128;
constexpr int NQG = BTOT / QPB;
constexpr int WAVES = 4;
constexpr int T1 = WAVES * 64;

__device__ __forceinline__ void load2fb(const float* __restrict__ p, float k[2][DIM]) {
    #pragma unroll
    for (int d = 0; d < DIM; ++d) k[0][d] = p[d];
    #pragma unroll
    for (int d = 0; d < DIM; ++d) k[1][d] = p[ROW + d];
}
__device__ __forceinline__ void compute2fb(
    const float k[2][DIM], const float qa[DIM], const float qb[DIM],
    float acca[DIM], float accb[DIM], float& la, float& lb)
{
    float sa0 = -SHIFT2, sb0 = -SHIFT2, sa1 = -SHIFT2, sb1 = -SHIFT2;
    #pragma unroll
    for (int d = 0; d < DIM; ++d) {
        sa0 = fmaf(qa[d], k[0][d], sa0);
        sb0 = fmaf(qb[d], k[0][d], sb0);
        sa1 = fmaf(qa[d], k[1][d], sa1);
        sb1 = fmaf(qb[d], k[1][d], sb1);
    }
    float ea0 = EXP2(sa0), eb0 = EXP2(sb0);
    float ea1 = EXP2(sa1), eb1 = EXP2(sb1);
    la += ea0 + ea1;
    lb += eb0 + eb1;
    #pragma unroll
    for (int d = 0; d < DIM; ++d) {
        acca[d] = fmaf(ea0, k[0][d], acca[d]);
        accb[d] = fmaf(eb0, k[0][d], accb[d]);
        acca[d] = fmaf(ea1, k[1][d], acca[d]);
        accb[d] = fmaf(eb1, k[1][d], accb[d]);
    }
}

template <int SL>
__global__ __launch_bounds__(T1, 4) void attn_partial_fb(
    const float* __restrict__ x, float* __restrict__ ws)
{
    constexpr int KPW = BTOT / SL / WAVES;
    __shared__ float rbuf[WAVES][QPB][13];

    const int bx = blockIdx.x;
    const int qg = bx / (NN * SL);
    const int r  = bx % (NN * SL);
    const int n  = r / SL;
    const int gc = r % SL;
    const int w  = __builtin_amdgcn_readfirstlane(threadIdx.x >> 6);
    const int j  = threadIdx.x & 63;

    float qa[DIM], qb[DIM];
    {
        const float* pa = x + (qg * QPB + j) * ROW + n * DIM;
        const float* pb = pa + 64 * ROW;
        #pragma unroll
        for (int d = 0; d < DIM; d += 2) {
            float2 ta = *(const float2*)(pa + d);
            float2 tb = *(const float2*)(pb + d);
            qa[d] = ta.x * LOG2E; qa[d + 1] = ta.y * LOG2E;
            qb[d] = tb.x * LOG2E; qb[d + 1] = tb.y * LOG2E;
        }
    }

    float la = 0.f, lb = 0.f;
    float acca[DIM], accb[DIM];
    #pragma unroll
    for (int d = 0; d < DIM; ++d) { acca[d] = 0.f; accb[d] = 0.f; }

    const int kbase = gc * (BTOT / SL) + w * KPW;
    const float* kp = x + (size_t)kbase * ROW + n * DIM;

    float kA[2][DIM], kB[2][DIM];
    load2fb(kp, kA);
    for (int kk = 0; kk < KPW - 4; kk += 4) {
        load2fb(kp + 2 * ROW, kB);
        compute2fb(kA, qa, qb, acca, accb, la, lb);
        load2fb(kp + 4 * ROW, kA);
        compute2fb(kB, qa, qb, acca, accb, la, lb);
        kp += 4 * ROW;
    }
    load2fb(kp + 2 * ROW, kB);
    compute2fb(kA, qa, qb, acca, accb, la, lb);
    compute2fb(kB, qa, qb, acca, accb, la, lb);

    #pragma unroll
    for (int d = 0; d < DIM; ++d) {
        rbuf[w][j][d]      = acca[d];
        rbuf[w][j + 64][d] = accb[d];
    }
    rbuf[w][j][DIM]      = la;
    rbuf[w][j + 64][DIM] = lb;
    __syncthreads();

    for (int t = threadIdx.x; t < (DIM + 1) * QPB; t += T1) {
        int d  = t >> 7;
        int jj = t & 127;
        float s = rbuf[0][jj][d] + rbuf[1][jj][d] + rbuf[2][jj][d] + rbuf[3][jj][d];
        ws[((size_t)(n * SL + gc) * BTOT + qg * QPB + jj) * 12 + d] = s;
    }
}

template <int SL>
__global__ __launch_bounds__(192) void finalize_fb(
    const float* __restrict__ ws, const float* __restrict__ A,
    const float* __restrict__ W, const float* __restrict__ bn_g,
    const float* __restrict__ bn_b, const float* __restrict__ bn_m,
    const float* __restrict__ bn_v, float* __restrict__ out)
{
    __shared__ float ubuf[64][NN][13];
    const int tl = threadIdx.x;
    const int ql = tl & 63;
    const int n  = tl >> 6;
    const int q  = blockIdx.x * 64 + ql;

    float a[12];
    #pragma unroll
    for (int d = 0; d < 12; ++d) a[d] = 0.f;
    #pragma unroll
    for (int sl = 0; sl < SL; ++sl) {
        const float* p = ws + ((size_t)(n * SL + sl) * BTOT + q) * 12;
        float4 v0 = *(const float4*)p;
        float4 v1 = *(const float4*)(p + 4);
        float4 v2 = *(const float4*)(p + 8);
        a[0] += v0.x; a[1] += v0.y; a[2]  += v0.z; a[3]  += v0.w;
        a[4] += v1.x; a[5] += v1.y; a[6]  += v1.z; a[7]  += v1.w;
        a[8] += v2.x; a[9] += v2.y; a[10] += v2.z;
    }
    float inv = 1.0f / a[10];
    float sc = bn_g[n] * rsqrtf(bn_v[n] + EPS);
    float sh = bn_b[n] - bn_m[n] * sc;
    float cw = 0.125f * (((n == 0) ? 0.f : 1.f) + A[n] +
                         ((n == 1) ? 0.f : 1.f) + A[NN + n]);
    #pragma unroll
    for (int d = 0; d < DIM; ++d)
        ubuf[ql][n][d] = cw * (a[d] * inv * sc + sh);
    __syncthreads();

    if (tl < 64) {
        float u[DIM];
        #pragma unroll
        for (int d = 0; d < DIM; ++d)
            u[d] = ubuf[ql][0][d] + ubuf[ql][1][d] + ubuf[ql][2][d];
        #pragma unroll
        for (int dout = 0; dout < DIM; ++dout) {
            float o = 0.f;
            #pragma unroll
            for (int e = 0; e < DIM; ++e) o = fmaf(u[e], W[e * DIM + dout], o);
            out[q * DIM + dout] = o;
        }
    }
}

// ------------------------------- launch ------------------------------------
extern "C" void kernel_launch(void* const* d_in, const int* in_sizes, int n_in,
                              void* d_out, int out_size, void* d_ws, size_t ws_size,
                              hipStream_t stream) {
    const float* x  = (const float*)d_in[0];
    const float* A  = (const float*)d_in[1];
    const float* W  = (const float*)d_in[2];
    const float* g  = (const float*)d_in[3];
    const float* be = (const float*)d_in[4];
    const float* mu = (const float*)d_in[5];
    const float* va = (const float*)d_in[6];
    float* out = (float*)d_out;

    const size_t FR_DW  = (size_t)NN * NTILE * 4 * 256;     // 393216 dwords
    const size_t PWS_DW = (size_t)NN * NKQ * BTOT * PSTR;   // 2359296 dwords
    const size_t needM  = (FR_DW + PWS_DW) * 4;             // ~11.0 MB

    if (ws_size >= needM) {
        unsigned* fr = (unsigned*)d_ws;
        float* pws   = (float*)d_ws + FR_DW;
        hipLaunchKernelGGL(prep_frags, dim3(NN * NTILE), dim3(256), 0, stream, x, fr);
        hipLaunchKernelGGL(attn_mfma, dim3((BTOT/128) * NN * NKQ), dim3(256), 0, stream,
                           fr, pws);
        hipLaunchKernelGGL(finalize2, dim3(BTOT / QB2), dim3(QB2 * NN * 16), 0, stream,
                           pws, A, W, g, be, mu, va, out);
    } else {
        float* ws = (float*)d_ws;
        auto need = [](int SL) { return (size_t)NN * SL * BTOT * 12 * sizeof(float); };
        if (ws_size >= need(16)) {
            hipLaunchKernelGGL((attn_partial_fb<16>), dim3(NQG * NN * 16), dim3(T1), 0, stream, x, ws);
            hipLaunchKernelGGL((finalize_fb<16>), dim3(BTOT / 64), dim3(192), 0, stream,
                               ws, A, W, g, be, mu, va, out);
        } else if (ws_size >= need(4)) {
            hipLaunchKernelGGL((attn_partial_fb<4>),  dim3(NQG * NN * 4),  dim3(T1), 0, stream, x, ws);
            hipLaunchKernelGGL((finalize_fb<4>),  dim3(BTOT / 64), dim3(192), 0, stream,
                               ws, A, W, g, be, mu, va, out);
        } else {
            hipLaunchKernelGGL((attn_partial_fb<1>),  dim3(NQG * NN * 1),  dim3(T1), 0, stream, x, ws);
            hipLaunchKernelGGL((finalize_fb<1>),  dim3(BTOT / 64), dim3(192), 0, stream,
                               ws, A, W, g, be, mu, va, out);
        }
    }
}

// Round 18
// 29.287 us; speedup vs baseline: 1.0224x; 1.0224x over previous
//
#include <hip/hip_runtime.h>
#include <hip/hip_bf16.h>
#include <math.h>

// ---------------------------------------------------------------------------
// MFMA-based fused GCN-attention (3 kernels) — r14 + block-level LDS tile
// sharing: the 4 waves of a block share one kq slice, so each tile is staged
// ONCE per block (global_load_lds, dbuf, 1 barrier/round) instead of loaded
// 4x redundantly from L2. fr traffic: 200 -> 55 MB.
//  K0 prep_frags: bf16 MFMA fragments (hi/lo split), per 32-key tile
//     [Ah | Al | Bx0 | Bx1] (1 KB each), linear stream (1.57 MB).
//  K1 attn_mfma: block = (qg, n, kq); wave w owns q-tile qg*4+w. 4 rounds of
//     4 tiles; wave w stages tile 4r+w into LDS; all waves compute all 4.
//     Per tile: S^T = mfma(Kh,Qh)+mfma(Kh,Ql)+mfma(Kl,Qh) (split precision),
//     p = exp2(S*LOG2E-SHIFT2) -> fast pack -> permlane32_swap -> P,
//     Cv += mfma(P0,Bx0)+mfma(P1,Bx1)  (V_hi | V_lo | l in one acc).
//     Store: v = hi + __shfl(lo) in-register, 11 columns (0-9 v, 10 l).
//  K2 finalize2: thread = (qLocal, n, slice); 8 slices in 8 consecutive
//     lanes -> 3-step __shfl_xor reduce; BN+adj -> ubuf; 1 barrier; W + pool.
// Fallback (small ws): round-7 scalar path (proven correct).
// ---------------------------------------------------------------------------

constexpr int BTOT = 4096;
constexpr int NN   = 3;
constexpr int DIM  = 10;
constexpr int ROW  = 30;          // floats per batch row
constexpr int NKQ  = 8;           // key eighths (512 keys each)
constexpr int NTILE= 128;         // 32-key tiles per node
constexpr int PSTR = 12;          // pws row stride (floats)
constexpr int QB2  = 16;          // queries per finalize2 block
constexpr float LOG2E  = 1.4426950408889634f;
constexpr float SHIFT2 = 20.0f * LOG2E;
constexpr float EPS = 1e-5f;

#if __has_builtin(__builtin_amdgcn_exp2f)
#define EXP2(x) __builtin_amdgcn_exp2f(x)
#else
#define EXP2(x) exp2f(x)
#endif

typedef __attribute__((ext_vector_type(8)))  short bf16x8;
typedef __attribute__((ext_vector_type(16))) float f32x16;

static __device__ __forceinline__ unsigned short bfbits(float x){
    __hip_bfloat16 h = __float2bfloat16(x);
    unsigned short u; __builtin_memcpy(&u, &h, 2); return u;
}
static __device__ __forceinline__ float bff(float x){
    return __bfloat162float(__float2bfloat16(x));
}
static __device__ __forceinline__ unsigned packbf(float lo, float hi){
    return ((unsigned)bfbits(hi) << 16) | bfbits(lo);   // RNE (prep only)
}
// fast pack: round-half-up via +0x8000, merge with one v_perm_b32 (proven r11/r13)
static __device__ __forceinline__ unsigned packbf_fast(float lo, float hi){
    unsigned ulo, uhi;
    __builtin_memcpy(&ulo, &lo, 4);
    __builtin_memcpy(&uhi, &hi, 4);
    ulo += 0x8000u; uhi += 0x8000u;
#if __has_builtin(__builtin_amdgcn_perm)
    return __builtin_amdgcn_perm(uhi, ulo, 0x07060302u);
#else
    return (uhi & 0xFFFF0000u) | (ulo >> 16);
#endif
}

// ------------------------------- K0: prep ----------------------------------
__global__ __launch_bounds__(256) void prep_frags(const float* __restrict__ x,
                                                  unsigned* __restrict__ fr)
{
    const int n = blockIdx.x >> 7;      // node
    const int t = blockIdx.x & 127;     // 32-key tile
    const int f = threadIdx.x >> 6;     // frag: 0=Ah 1=Al 2=Bx0 3=Bx1
    const int l = threadIdx.x & 63;     // frag lane
    const int h = l >> 5;
    unsigned o[4];
    if (f < 2) {
        // A-frag: lane l holds A[key = 32t+(l&31)][feat = 8h+b], b=0..7
        const float* xp = x + (size_t)(32*t + (l & 31)) * ROW + n * DIM;
        #pragma unroll
        for (int w = 0; w < 4; ++w) {
            const int f0 = 8*h + 2*w;
            float x0 = (f0     < DIM) ? xp[f0]     : 0.f;
            float x1 = (f0 + 1 < DIM) ? xp[f0 + 1] : 0.f;
            o[w] = (f == 0) ? packbf(x0, x1)
                            : packbf(x0 - bff(x0), x1 - bff(x1));
        }
    } else {
        // Bx-frag chunk c: lane l holds B[kk = 8h+b][col = l&31],
        // key = 32t+16c+kk; col: 0-9 x_hi, 10-19 x_lo, 20 ones, 21-31 zero
        const int c  = f - 2;
        const int dp = l & 31;
        #pragma unroll
        for (int w = 0; w < 4; ++w) {
            float v[2];
            #pragma unroll
            for (int e = 0; e < 2; ++e) {
                const int r = 32*t + 16*c + 8*h + 2*w + e;
                float val;
                if (dp < DIM) {
                    val = bff(x[(size_t)r*ROW + n*DIM + dp]);
                } else if (dp < 2*DIM) {
                    float xx = x[(size_t)r*ROW + n*DIM + dp - DIM];
                    val = xx - bff(xx);
                } else {
                    val = (dp == 2*DIM) ? 1.0f : 0.0f;
                }
                v[e] = val;
            }
            o[w] = packbf(v[0], v[1]);
        }
    }
    unsigned* dst = fr + ((((size_t)n*NTILE + t)*4 + f) << 8) + l*4;
    *(uint4*)dst = make_uint4(o[0], o[1], o[2], o[3]);
}

// ------------------------------- K1: attention -----------------------------
union FU { uint4 q; bf16x8 v; };

__device__ __forceinline__ void computeTileLDS(const unsigned* __restrict__ kp,
                                               int l,
                                               const FU& quh, const FU& qul,
                                               f32x16& Cv)
{
    // kp = LDS tile base (4 frags x 1KB); per-lane stride-1 reads (no conflict)
    FU fAh, fAl, fB0, fB1;
    fAh.q = *(const uint4*)(kp + l*4);
    fAl.q = *(const uint4*)(kp + 256 + l*4);
    fB0.q = *(const uint4*)(kp + 512 + l*4);
    fB1.q = *(const uint4*)(kp + 768 + l*4);

    // S^T (32k x 32q), split precision: Kh*Qh + Kh*Ql + Kl*Qh
    f32x16 S;
    #pragma unroll
    for (int i = 0; i < 16; ++i) S[i] = 0.f;
    S = __builtin_amdgcn_mfma_f32_32x32x16_bf16(fAh.v, quh.v, S, 0, 0, 0);
    S = __builtin_amdgcn_mfma_f32_32x32x16_bf16(fAh.v, qul.v, S, 0, 0, 0);
    S = __builtin_amdgcn_mfma_f32_32x32x16_bf16(fAl.v, quh.v, S, 0, 0, 0);

    // p = exp2(LOG2E*S - SHIFT2); lane holds k = (reg&3)+8*(reg>>2)+4h
    float p[16];
    #pragma unroll
    for (int i = 0; i < 16; ++i) p[i] = EXP2(fmaf(S[i], LOG2E, -SHIFT2));

    // pack pairs then swap across lane<32/lane>=32 halves
    unsigned W0[2] = {packbf_fast(p[0],  p[1]),  packbf_fast(p[2],  p[3])};
    unsigned W1[2] = {packbf_fast(p[4],  p[5]),  packbf_fast(p[6],  p[7])};
    unsigned W2[2] = {packbf_fast(p[8],  p[9]),  packbf_fast(p[10], p[11])};
    unsigned W3[2] = {packbf_fast(p[12], p[13]), packbf_fast(p[14], p[15])};
    asm("v_permlane32_swap_b32 %0, %1" : "+v"(W0[0]), "+v"(W1[0]));
    asm("v_permlane32_swap_b32 %0, %1" : "+v"(W0[1]), "+v"(W1[1]));
    asm("v_permlane32_swap_b32 %0, %1" : "+v"(W2[0]), "+v"(W3[0]));
    asm("v_permlane32_swap_b32 %0, %1" : "+v"(W2[1]), "+v"(W3[1]));

    FU P0, P1;
    P0.q = make_uint4(W0[0], W0[1], W1[0], W1[1]);  // keys 0..15 of tile
    P1.q = make_uint4(W2[0], W2[1], W3[0], W3[1]);  // keys 16..31

    Cv = __builtin_amdgcn_mfma_f32_32x32x16_bf16(P0.v, fB0.v, Cv, 0, 0, 0);
    Cv = __builtin_amdgcn_mfma_f32_32x32x16_bf16(P1.v, fB1.v, Cv, 0, 0, 0);
}

__global__ __launch_bounds__(256, 3) void attn_mfma(
    const unsigned* __restrict__ fr, float* __restrict__ pws)
{
    // [buf][tile-in-round][4 frags x 256 uints] = 32 KB
    __shared__ unsigned kb[2][4][1024];

    const int bx  = blockIdx.x;
    const int qg  = bx / (NN*NKQ);
    const int rem = bx % (NN*NKQ);
    const int n   = rem / NKQ;
    const int kq  = rem % NKQ;
    const int w   = threadIdx.x >> 6;
    const int l   = threadIdx.x & 63;
    const int qt  = qg*4 + w;           // this wave's 32-q tile

    // Q-side frags (hi/lo) = Ah/Al of tile qt (identical byte layout)
    FU quh, qul;
    {
        const unsigned* p = fr + ((((size_t)n*NTILE + qt)*4) << 8) + l*4;
        quh.q = *(const uint4*)p;
        qul.q = *(const uint4*)(p + 256);
    }

    f32x16 Cv;
    #pragma unroll
    for (int i = 0; i < 16; ++i) Cv[i] = 0.f;

    const int t0 = kq * 16;

    // wave w stages tile 4r+w (4 KB = 4 x global_load_lds width-16)
    auto stage = [&](int r, int b) {
        const int t = t0 + 4*r + w;
        const unsigned* g = fr + ((((size_t)n*NTILE + t)*4) << 8) + l*4;
        #pragma unroll
        for (int f = 0; f < 4; ++f) {
            __builtin_amdgcn_global_load_lds(
                (const __attribute__((address_space(1))) unsigned*)(g + f*256),
                (__attribute__((address_space(3))) unsigned*)&kb[b][w][f*256],
                16, 0, 0);
        }
    };

    stage(0, 0);
    __syncthreads();            // round-0 tiles staged (vmcnt drained by HIP)

    #pragma unroll
    for (int r = 0; r < 4; ++r) {
        if (r < 3) stage(r + 1, (r + 1) & 1);   // prefetch next round
        const unsigned* kbase = &kb[r & 1][0][0];
        computeTileLDS(kbase,        l, quh, qul, Cv);
        computeTileLDS(kbase + 1024, l, quh, qul, Cv);
        computeTileLDS(kbase + 2048, l, quh, qul, Cv);
        computeTileLDS(kbase + 3072, l, quh, qul, Cv);
        __syncthreads();        // drain prefetch (hidden under ~700cy compute)
    }

    // in-register hi+lo combine: lane dp (<10) adds lane dp+10's Cv.
    float add10[16];
    #pragma unroll
    for (int r = 0; r < 16; ++r) add10[r] = __shfl(Cv[r], l + 10);

    // store 11 columns: 0-9 = v (hi+lo), 10 = l-sum
    const int dp = l & 31;
    const int h  = l >> 5;
    if (dp < DIM || dp == 2*DIM) {
        const int col = (dp < DIM) ? dp : DIM;
        float* base = pws + (((size_t)(n*NKQ + kq)*BTOT) + qt*32) * PSTR + col;
        #pragma unroll
        for (int r = 0; r < 16; ++r) {
            const int q = (r & 3) + 8*(r >> 2) + 4*h;
            float v = Cv[r];
            if (dp < DIM) v += add10[r];
            base[q * PSTR] = v;
        }
    }
}

// ------------------------------- K2: finalize2 -----------------------------
// thread = (qLocal, n, slice): tid = (qLocal*NN + n)*8 + slice.
// 8 slices are 8 consecutive lanes (aligned) -> shfl_xor reduce in-wave.
__global__ __launch_bounds__(QB2 * NN * 8) void finalize2(
    const float* __restrict__ pws, const float* __restrict__ A,
    const float* __restrict__ W, const float* __restrict__ bn_g,
    const float* __restrict__ bn_b, const float* __restrict__ bn_m,
    const float* __restrict__ bn_v, float* __restrict__ out)
{
    __shared__ float ubuf[QB2][NN][11];   // 2.1 KB
    const int tid   = threadIdx.x;        // 384
    const int slice = tid & 7;
    const int row   = tid >> 3;           // 0..47
    const int n     = row % NN;
    const int qL    = row / NN;
    const int q     = blockIdx.x * QB2 + qL;

    // read this slice's 11 partials
    const float* p = pws + ((size_t)((n*NKQ + slice)*BTOT) + q) * PSTR;
    float4 v0 = *(const float4*)(p);
    float4 v1 = *(const float4*)(p + 4);
    float2 v2 = *(const float2*)(p + 8);
    float  lv = p[10];
    float acc[11] = {v0.x, v0.y, v0.z, v0.w, v1.x, v1.y, v1.z, v1.w,
                     v2.x, v2.y, lv};

    // butterfly reduce over the 8 slices (3 steps, in-wave)
    #pragma unroll
    for (int m = 1; m < 8; m <<= 1) {
        #pragma unroll
        for (int i = 0; i < 11; ++i) acc[i] += __shfl_xor(acc[i], m);
    }

    if (slice == 0) {
        const float inv = 1.0f / acc[10];
        const float sc  = bn_g[n] * rsqrtf(bn_v[n] + EPS);
        const float sh  = bn_b[n] - bn_m[n] * sc;
        const float cw  = 0.125f * (((n == 0) ? 0.f : 1.f) + A[n] +
                                    ((n == 1) ? 0.f : 1.f) + A[NN + n]);
        #pragma unroll
        for (int d = 0; d < DIM; ++d)
            ubuf[qL][n][d] = cw * (acc[d] * inv * sc + sh);
    }
    __syncthreads();

    // 160 threads: out[q][dout] = sum_e (sum_n ubuf[qL][n][e]) * W[e][dout]
    if (tid < QB2 * DIM) {
        const int qL2  = tid / DIM;
        const int dout = tid - qL2 * DIM;
        float o = 0.f;
        #pragma unroll
        for (int e = 0; e < DIM; ++e) {
            float u = ubuf[qL2][0][e] + ubuf[qL2][1][e] + ubuf[qL2][2][e];
            o = fmaf(u, W[e*DIM + dout], o);
        }
        out[(blockIdx.x * QB2 + qL2) * DIM + dout] = o;
    }
}

// --------------------------- fallback (round-7, proven) --------------------
constexpr int QPB = 128;
constexpr int NQG = BTOT / QPB;
constexpr int WAVES = 4;
constexpr int T1 = WAVES * 64;

__device__ __forceinline__ void load2fb(const float* __restrict__ p, float k[2][DIM]) {
    #pragma unroll
    for (int d = 0; d < DIM; ++d) k[0][d] = p[d];
    #pragma unroll
    for (int d = 0; d < DIM; ++d) k[1][d] = p[ROW + d];
}
__device__ __forceinline__ void compute2fb(
    const float k[2][DIM], const float qa[DIM], const float qb[DIM],
    float acca[DIM], float accb[DIM], float& la, float& lb)
{
    float sa0 = -SHIFT2, sb0 = -SHIFT2, sa1 = -SHIFT2, sb1 = -SHIFT2;
    #pragma unroll
    for (int d = 0; d < DIM; ++d) {
        sa0 = fmaf(qa[d], k[0][d], sa0);
        sb0 = fmaf(qb[d], k[0][d], sb0);
        sa1 = fmaf(qa[d], k[1][d], sa1);
        sb1 = fmaf(qb[d], k[1][d], sb1);
    }
    float ea0 = EXP2(sa0), eb0 = EXP2(sb0);
    float ea1 = EXP2(sa1), eb1 = EXP2(sb1);
    la += ea0 + ea1;
    lb += eb0 + eb1;
    #pragma unroll
    for (int d = 0; d < DIM; ++d) {
        acca[d] = fmaf(ea0, k[0][d], acca[d]);
        accb[d] = fmaf(eb0, k[0][d], accb[d]);
        acca[d] = fmaf(ea1, k[1][d], acca[d]);
        accb[d] = fmaf(eb1, k[1][d], accb[d]);
    }
}

template <int SL>
__global__ __launch_bounds__(T1, 4) void attn_partial_fb(
    const float* __restrict__ x, float* __restrict__ ws)
{
    constexpr int KPW = BTOT / SL / WAVES;
    __shared__ float rbuf[WAVES][QPB][13];

    const int bx = blockIdx.x;
    const int qg = bx / (NN * SL);
    const int r  = bx % (NN * SL);
    const int n  = r / SL;
    const int gc = r % SL;
    const int w  = __builtin_amdgcn_readfirstlane(threadIdx.x >> 6);
    const int j  = threadIdx.x & 63;

    float qa[DIM], qb[DIM];
    {
        const float* pa = x + (qg * QPB + j) * ROW + n * DIM;
        const float* pb = pa + 64 * ROW;
        #pragma unroll
        for (int d = 0; d < DIM; d += 2) {
            float2 ta = *(const float2*)(pa + d);
            float2 tb = *(const float2*)(pb + d);
            qa[d] = ta.x * LOG2E; qa[d + 1] = ta.y * LOG2E;
            qb[d] = tb.x * LOG2E; qb[d + 1] = tb.y * LOG2E;
        }
    }

    float la = 0.f, lb = 0.f;
    float acca[DIM], accb[DIM];
    #pragma unroll
    for (int d = 0; d < DIM; ++d) { acca[d] = 0.f; accb[d] = 0.f; }

    const int kbase = gc * (BTOT / SL) + w * KPW;
    const float* kp = x + (size_t)kbase * ROW + n * DIM;

    float kA[2][DIM], kB[2][DIM];
    load2fb(kp, kA);
    for (int kk = 0; kk < KPW - 4; kk += 4) {
        load2fb(kp + 2 * ROW, kB);
        compute2fb(kA, qa, qb, acca, accb, la, lb);
        load2fb(kp + 4 * ROW, kA);
        compute2fb(kB, qa, qb, acca, accb, la, lb);
        kp += 4 * ROW;
    }
    load2fb(kp + 2 * ROW, kB);
    compute2fb(kA, qa, qb, acca, accb, la, lb);
    compute2fb(kB, qa, qb, acca, accb, la, lb);

    #pragma unroll
    for (int d = 0; d < DIM; ++d) {
        rbuf[w][j][d]      = acca[d];
        rbuf[w][j + 64][d] = accb[d];
    }
    rbuf[w][j][DIM]      = la;
    rbuf[w][j + 64][DIM] = lb;
    __syncthreads();

    for (int t = threadIdx.x; t < (DIM + 1) * QPB; t += T1) {
        int d  = t >> 7;
        int jj = t & 127;
        float s = rbuf[0][jj][d] + rbuf[1][jj][d] + rbuf[2][jj][d] + rbuf[3][jj][d];
        ws[((size_t)(n * SL + gc) * BTOT + qg * QPB + jj) * 12 + d] = s;
    }
}

template <int SL>
__global__ __launch_bounds__(192) void finalize_fb(
    const float* __restrict__ ws, const float* __restrict__ A,
    const float* __restrict__ W, const float* __restrict__ bn_g,
    const float* __restrict__ bn_b, const float* __restrict__ bn_m,
    const float* __restrict__ bn_v, float* __restrict__ out)
{
    __shared__ float ubuf[64][NN][13];
    const int tl = threadIdx.x;
    const int ql = tl & 63;
    const int n  = tl >> 6;
    const int q  = blockIdx.x * 64 + ql;

    float a[12];
    #pragma unroll
    for (int d = 0; d < 12; ++d) a[d] = 0.f;
    #pragma unroll
    for (int sl = 0; sl < SL; ++sl) {
        const float* p = ws + ((size_t)(n * SL + sl) * BTOT + q) * 12;
        float4 v0 = *(const float4*)p;
        float4 v1 = *(const float4*)(p + 4);
        float4 v2 = *(const float4*)(p + 8);
        a[0] += v0.x; a[1] += v0.y; a[2]  += v0.z; a[3]  += v0.w;
        a[4] += v1.x; a[5] += v1.y; a[6]  += v1.z; a[7]  += v1.w;
        a[8] += v2.x; a[9] += v2.y; a[10] += v2.z;
    }
    float inv = 1.0f / a[10];
    float sc = bn_g[n] * rsqrtf(bn_v[n] + EPS);
    float sh = bn_b[n] - bn_m[n] * sc;
    float cw = 0.125f * (((n == 0) ? 0.f : 1.f) + A[n] +
                         ((n == 1) ? 0.f : 1.f) + A[NN + n]);
    #pragma unroll
    for (int d = 0; d < DIM; ++d)
        ubuf[ql][n][d] = cw * (a[d] * inv * sc + sh);
    __syncthreads();

    if (tl < 64) {
        float u[DIM];
        #pragma unroll
        for (int d = 0; d < DIM; ++d)
            u[d] = ubuf[ql][0][d] + ubuf[ql][1][d] + ubuf[ql][2][d];
        #pragma unroll
        for (int dout = 0; dout < DIM; ++dout) {
            float o = 0.f;
            #pragma unroll
            for (int e = 0; e < DIM; ++e) o = fmaf(u[e], W[e * DIM + dout], o);
            out[q * DIM + dout] = o;
        }
    }
}

// ------------------------------- launch ------------------------------------
extern "C" void kernel_launch(void* const* d_in, const int* in_sizes, int n_in,
                              void* d_out, int out_size, void* d_ws, size_t ws_size,
                              hipStream_t stream) {
    const float* x  = (const float*)d_in[0];
    const float* A  = (const float*)d_in[1];
    const float* W  = (const float*)d_in[2];
    const float* g  = (const float*)d_in[3];
    const float* be = (const float*)d_in[4];
    const float* mu = (const float*)d_in[5];
    const float* va = (const float*)d_in[6];
    float* out = (float*)d_out;

    const size_t FR_DW  = (size_t)NN * NTILE * 4 * 256;     // 393216 dwords
    const size_t PWS_DW = (size_t)NN * NKQ * BTOT * PSTR;   // 1179648 dwords
    const size_t needM  = (FR_DW + PWS_DW) * 4;             // ~6.3 MB

    if (ws_size >= needM) {
        unsigned* fr = (unsigned*)d_ws;
        float* pws   = (float*)d_ws + FR_DW;
        hipLaunchKernelGGL(prep_frags, dim3(NN * NTILE), dim3(256), 0, stream, x, fr);
        hipLaunchKernelGGL(attn_mfma, dim3((BTOT/128) * NN * NKQ), dim3(256), 0, stream,
                           fr, pws);
        hipLaunchKernelGGL(finalize2, dim3(BTOT / QB2), dim3(QB2 * NN * 8), 0, stream,
                           pws, A, W, g, be, mu, va, out);
    } else {
        float* ws = (float*)d_ws;
        auto need = [](int SL) { return (size_t)NN * SL * BTOT * 12 * sizeof(float); };
        if (ws_size >= need(16)) {
            hipLaunchKernelGGL((attn_partial_fb<16>), dim3(NQG * NN * 16), dim3(T1), 0, stream, x, ws);
            hipLaunchKernelGGL((finalize_fb<16>), dim3(BTOT / 64), dim3(192), 0, stream,
                               ws, A, W, g, be, mu, va, out);
        } else if (ws_size >= need(4)) {
            hipLaunchKernelGGL((attn_partial_fb<4>),  dim3(NQG * NN * 4),  dim3(T1), 0, stream, x, ws);
            hipLaunchKernelGGL((finalize_fb<4>),  dim3(BTOT / 64), dim3(192), 0, stream,
                               ws, A, W, g, be, mu, va, out);
        } else {
            hipLaunchKernelGGL((attn_partial_fb<1>),  dim3(NQG * NN * 1),  dim3(T1), 0, stream, x, ws);
            hipLaunchKernelGGL((finalize_fb<1>),  dim3(BTOT / 64), dim3(192), 0, stream,
                               ws, A, W, g, be, mu, va, out);
        }
    }
}

// Round 19
// 27.000 us; speedup vs baseline: 1.1091x; 1.0847x over previous
//
#include <hip/hip_runtime.h>
#include <hip/hip_bf16.h>
#include <math.h>

// ---------------------------------------------------------------------------
// MFMA-based fused GCN-attention (3 kernels) — ROUND-14 CHAMPION (27.0 us),
// reverted verbatim after r15-r18 (ILP, prefetch depth, occupancy, LDS
// sharing) all regressed or were neutral:
//  K0 prep_frags: bf16 MFMA fragments (hi/lo split), per 32-key tile
//     [Ah | Al | Bx0 | Bx1] (1 KB each), linear stream (1.57 MB).
//  K1 attn_mfma: per wave: 32-q tile, 512-key slice. Frags global->VGPR,
//     explicit ping-pong, zero LDS, zero barriers:
//       S^T = mfma(Kh,Qh)+mfma(Kh,Ql)+mfma(Kl,Qh)   (split precision)
//       p = exp2(S*LOG2E-SHIFT2) -> fast pack -> permlane32_swap -> P
//       Cv += mfma(P0,Bx0)+mfma(P1,Bx1)   (V_hi | V_lo | l in one acc)
//     Store: v = hi + __shfl(lo) in-register, 11 columns (0-9 v, 10 l).
//  K2 finalize2: thread = (qLocal, n, slice); 8 slices in 8 consecutive
//     lanes -> 3-step __shfl_xor reduce; BN+adj -> ubuf; 1 barrier; W + pool.
// Fallback (small ws): round-7 scalar path (proven correct).
// ---------------------------------------------------------------------------

constexpr int BTOT = 4096;
constexpr int NN   = 3;
constexpr int DIM  = 10;
constexpr int ROW  = 30;          // floats per batch row
constexpr int NKQ  = 8;           // key eighths (512 keys each)
constexpr int NTILE= 128;         // 32-key tiles per node
constexpr int PSTR = 12;          // pws row stride (floats)
constexpr int QB2  = 16;          // queries per finalize2 block
constexpr float LOG2E  = 1.4426950408889634f;
constexpr float SHIFT2 = 20.0f * LOG2E;
constexpr float EPS = 1e-5f;

#if __has_builtin(__builtin_amdgcn_exp2f)
#define EXP2(x) __builtin_amdgcn_exp2f(x)
#else
#define EXP2(x) exp2f(x)
#endif

typedef __attribute__((ext_vector_type(8)))  short bf16x8;
typedef __attribute__((ext_vector_type(16))) float f32x16;

static __device__ __forceinline__ unsigned short bfbits(float x){
    __hip_bfloat16 h = __float2bfloat16(x);
    unsigned short u; __builtin_memcpy(&u, &h, 2); return u;
}
static __device__ __forceinline__ float bff(float x){
    return __bfloat162float(__float2bfloat16(x));
}
static __device__ __forceinline__ unsigned packbf(float lo, float hi){
    return ((unsigned)bfbits(hi) << 16) | bfbits(lo);   // RNE (prep only)
}
// fast pack: round-half-up via +0x8000, merge with one v_perm_b32 (proven r11/r13)
static __device__ __forceinline__ unsigned packbf_fast(float lo, float hi){
    unsigned ulo, uhi;
    __builtin_memcpy(&ulo, &lo, 4);
    __builtin_memcpy(&uhi, &hi, 4);
    ulo += 0x8000u; uhi += 0x8000u;
#if __has_builtin(__builtin_amdgcn_perm)
    return __builtin_amdgcn_perm(uhi, ulo, 0x07060302u);
#else
    return (uhi & 0xFFFF0000u) | (ulo >> 16);
#endif
}

// ------------------------------- K0: prep ----------------------------------
__global__ __launch_bounds__(256) void prep_frags(const float* __restrict__ x,
                                                  unsigned* __restrict__ fr)
{
    const int n = blockIdx.x >> 7;      // node
    const int t = blockIdx.x & 127;     // 32-key tile
    const int f = threadIdx.x >> 6;     // frag: 0=Ah 1=Al 2=Bx0 3=Bx1
    const int l = threadIdx.x & 63;     // frag lane
    const int h = l >> 5;
    unsigned o[4];
    if (f < 2) {
        // A-frag: lane l holds A[key = 32t+(l&31)][feat = 8h+b], b=0..7
        const float* xp = x + (size_t)(32*t + (l & 31)) * ROW + n * DIM;
        #pragma unroll
        for (int w = 0; w < 4; ++w) {
            const int f0 = 8*h + 2*w;
            float x0 = (f0     < DIM) ? xp[f0]     : 0.f;
            float x1 = (f0 + 1 < DIM) ? xp[f0 + 1] : 0.f;
            o[w] = (f == 0) ? packbf(x0, x1)
                            : packbf(x0 - bff(x0), x1 - bff(x1));
        }
    } else {
        // Bx-frag chunk c: lane l holds B[kk = 8h+b][col = l&31],
        // key = 32t+16c+kk; col: 0-9 x_hi, 10-19 x_lo, 20 ones, 21-31 zero
        const int c  = f - 2;
        const int dp = l & 31;
        #pragma unroll
        for (int w = 0; w < 4; ++w) {
            float v[2];
            #pragma unroll
            for (int e = 0; e < 2; ++e) {
                const int r = 32*t + 16*c + 8*h + 2*w + e;
                float val;
                if (dp < DIM) {
                    val = bff(x[(size_t)r*ROW + n*DIM + dp]);
                } else if (dp < 2*DIM) {
                    float xx = x[(size_t)r*ROW + n*DIM + dp - DIM];
                    val = xx - bff(xx);
                } else {
                    val = (dp == 2*DIM) ? 1.0f : 0.0f;
                }
                v[e] = val;
            }
            o[w] = packbf(v[0], v[1]);
        }
    }
    unsigned* dst = fr + ((((size_t)n*NTILE + t)*4 + f) << 8) + l*4;
    *(uint4*)dst = make_uint4(o[0], o[1], o[2], o[3]);
}

// ------------------------------- K1: attention -----------------------------
union FU { uint4 q; bf16x8 v; };
struct Tile { FU fAh, fAl, fB0, fB1; };

__device__ __forceinline__ void loadTile(const unsigned* __restrict__ fr,
                                         int n, int t, int l, Tile& T)
{
    const unsigned* p = fr + ((((size_t)n*NTILE + t)*4) << 8) + l*4;
    T.fAh.q = *(const uint4*)(p);
    T.fAl.q = *(const uint4*)(p + 256);
    T.fB0.q = *(const uint4*)(p + 512);
    T.fB1.q = *(const uint4*)(p + 768);
}

__device__ __forceinline__ void computeTile(const Tile& T,
                                            const FU& quh, const FU& qul,
                                            f32x16& Cv)
{
    // S^T (32k x 32q), split precision: Kh*Qh + Kh*Ql + Kl*Qh
    f32x16 S;
    #pragma unroll
    for (int i = 0; i < 16; ++i) S[i] = 0.f;
    S = __builtin_amdgcn_mfma_f32_32x32x16_bf16(T.fAh.v, quh.v, S, 0, 0, 0);
    S = __builtin_amdgcn_mfma_f32_32x32x16_bf16(T.fAh.v, qul.v, S, 0, 0, 0);
    S = __builtin_amdgcn_mfma_f32_32x32x16_bf16(T.fAl.v, quh.v, S, 0, 0, 0);

    // p = exp2(LOG2E*S - SHIFT2); lane holds k = (reg&3)+8*(reg>>2)+4h
    float p[16];
    #pragma unroll
    for (int i = 0; i < 16; ++i) p[i] = EXP2(fmaf(S[i], LOG2E, -SHIFT2));

    // pack pairs then swap across lane<32/lane>=32 halves
    unsigned W0[2] = {packbf_fast(p[0],  p[1]),  packbf_fast(p[2],  p[3])};
    unsigned W1[2] = {packbf_fast(p[4],  p[5]),  packbf_fast(p[6],  p[7])};
    unsigned W2[2] = {packbf_fast(p[8],  p[9]),  packbf_fast(p[10], p[11])};
    unsigned W3[2] = {packbf_fast(p[12], p[13]), packbf_fast(p[14], p[15])};
    asm("v_permlane32_swap_b32 %0, %1" : "+v"(W0[0]), "+v"(W1[0]));
    asm("v_permlane32_swap_b32 %0, %1" : "+v"(W0[1]), "+v"(W1[1]));
    asm("v_permlane32_swap_b32 %0, %1" : "+v"(W2[0]), "+v"(W3[0]));
    asm("v_permlane32_swap_b32 %0, %1" : "+v"(W2[1]), "+v"(W3[1]));

    FU P0, P1;
    P0.q = make_uint4(W0[0], W0[1], W1[0], W1[1]);  // keys 0..15 of tile
    P1.q = make_uint4(W2[0], W2[1], W3[0], W3[1]);  // keys 16..31

    Cv = __builtin_amdgcn_mfma_f32_32x32x16_bf16(P0.v, T.fB0.v, Cv, 0, 0, 0);
    Cv = __builtin_amdgcn_mfma_f32_32x32x16_bf16(P1.v, T.fB1.v, Cv, 0, 0, 0);
}

__global__ __launch_bounds__(256, 3) void attn_mfma(
    const unsigned* __restrict__ fr, float* __restrict__ pws)
{
    const int bx  = blockIdx.x;
    const int qg  = bx / (NN*NKQ);
    const int rem = bx % (NN*NKQ);
    const int n   = rem / NKQ;
    const int kq  = rem % NKQ;
    const int w   = threadIdx.x >> 6;
    const int l   = threadIdx.x & 63;
    const int qt  = qg*4 + w;           // this wave's 32-q tile

    // Q-side frags (hi/lo) = Ah/Al of tile qt (identical byte layout)
    FU quh, qul;
    {
        const unsigned* p = fr + ((((size_t)n*NTILE + qt)*4) << 8) + l*4;
        quh.q = *(const uint4*)p;
        qul.q = *(const uint4*)(p + 256);
    }

    f32x16 Cv;
    #pragma unroll
    for (int i = 0; i < 16; ++i) Cv[i] = 0.f;

    const int t0 = kq * 16;

    // ping-pong: zero LDS, zero barriers, loads overlap compute
    Tile TA, TB;
    loadTile(fr, n, t0, l, TA);
    #pragma unroll
    for (int it = 0; it < 7; ++it) {
        loadTile(fr, n, t0 + 2*it + 1, l, TB);
        computeTile(TA, quh, qul, Cv);
        loadTile(fr, n, t0 + 2*it + 2, l, TA);
        computeTile(TB, quh, qul, Cv);
    }
    loadTile(fr, n, t0 + 15, l, TB);
    computeTile(TA, quh, qul, Cv);
    computeTile(TB, quh, qul, Cv);

    // in-register hi+lo combine: lane dp (<10) adds lane dp+10's Cv.
    float add10[16];
    #pragma unroll
    for (int r = 0; r < 16; ++r) add10[r] = __shfl(Cv[r], l + 10);

    // store 11 columns: 0-9 = v (hi+lo), 10 = l-sum
    const int dp = l & 31;
    const int h  = l >> 5;
    if (dp < DIM || dp == 2*DIM) {
        const int col = (dp < DIM) ? dp : DIM;
        float* base = pws + (((size_t)(n*NKQ + kq)*BTOT) + qt*32) * PSTR + col;
        #pragma unroll
        for (int r = 0; r < 16; ++r) {
            const int q = (r & 3) + 8*(r >> 2) + 4*h;
            float v = Cv[r];
            if (dp < DIM) v += add10[r];
            base[q * PSTR] = v;
        }
    }
}

// ------------------------------- K2: finalize2 -----------------------------
// thread = (qLocal, n, slice): tid = (qLocal*NN + n)*8 + slice.
// 8 slices are 8 consecutive lanes (aligned) -> shfl_xor reduce in-wave.
__global__ __launch_bounds__(QB2 * NN * 8) void finalize2(
    const float* __restrict__ pws, const float* __restrict__ A,
    const float* __restrict__ W, const float* __restrict__ bn_g,
    const float* __restrict__ bn_b, const float* __restrict__ bn_m,
    const float* __restrict__ bn_v, float* __restrict__ out)
{
    __shared__ float ubuf[QB2][NN][11];   // 2.1 KB
    const int tid   = threadIdx.x;        // 384
    const int slice = tid & 7;
    const int row   = tid >> 3;           // 0..47
    const int n     = row % NN;
    const int qL    = row / NN;
    const int q     = blockIdx.x * QB2 + qL;

    // read this slice's 11 partials
    const float* p = pws + ((size_t)((n*NKQ + slice)*BTOT) + q) * PSTR;
    float4 v0 = *(const float4*)(p);
    float4 v1 = *(const float4*)(p + 4);
    float2 v2 = *(const float2*)(p + 8);
    float  lv = p[10];
    float acc[11] = {v0.x, v0.y, v0.z, v0.w, v1.x, v1.y, v1.z, v1.w,
                     v2.x, v2.y, lv};

    // butterfly reduce over the 8 slices (3 steps, in-wave)
    #pragma unroll
    for (int m = 1; m < 8; m <<= 1) {
        #pragma unroll
        for (int i = 0; i < 11; ++i) acc[i] += __shfl_xor(acc[i], m);
    }

    if (slice == 0) {
        const float inv = 1.0f / acc[10];
        const float sc  = bn_g[n] * rsqrtf(bn_v[n] + EPS);
        const float sh  = bn_b[n] - bn_m[n] * sc;
        const float cw  = 0.125f * (((n == 0) ? 0.f : 1.f) + A[n] +
                                    ((n == 1) ? 0.f : 1.f) + A[NN + n]);
        #pragma unroll
        for (int d = 0; d < DIM; ++d)
            ubuf[qL][n][d] = cw * (acc[d] * inv * sc + sh);
    }
    __syncthreads();

    // 160 threads: out[q][dout] = sum_e (sum_n ubuf[qL][n][e]) * W[e][dout]
    if (tid < QB2 * DIM) {
        const int qL2  = tid / DIM;
        const int dout = tid - qL2 * DIM;
        float o = 0.f;
        #pragma unroll
        for (int e = 0; e < DIM; ++e) {
            float u = ubuf[qL2][0][e] + ubuf[qL2][1][e] + ubuf[qL2][2][e];
            o = fmaf(u, W[e*DIM + dout], o);
        }
        out[(blockIdx.x * QB2 + qL2) * DIM + dout] = o;
    }
}

// --------------------------- fallback (round-7, proven) --------------------
constexpr int QPB = 128;
constexpr int NQG = BTOT / QPB;
constexpr int WAVES = 4;
constexpr int T1 = WAVES * 64;

__device__ __forceinline__ void load2fb(const float* __restrict__ p, float k[2][DIM]) {
    #pragma unroll
    for (int d = 0; d < DIM; ++d) k[0][d] = p[d];
    #pragma unroll
    for (int d = 0; d < DIM; ++d) k[1][d] = p[ROW + d];
}
__device__ __forceinline__ void compute2fb(
    const float k[2][DIM], const float qa[DIM], const float qb[DIM],
    float acca[DIM], float accb[DIM], float& la, float& lb)
{
    float sa0 = -SHIFT2, sb0 = -SHIFT2, sa1 = -SHIFT2, sb1 = -SHIFT2;
    #pragma unroll
    for (int d = 0; d < DIM; ++d) {
        sa0 = fmaf(qa[d], k[0][d], sa0);
        sb0 = fmaf(qb[d], k[0][d], sb0);
        sa1 = fmaf(qa[d], k[1][d], sa1);
        sb1 = fmaf(qb[d], k[1][d], sb1);
    }
    float ea0 = EXP2(sa0), eb0 = EXP2(sb0);
    float ea1 = EXP2(sa1), eb1 = EXP2(sb1);
    la += ea0 + ea1;
    lb += eb0 + eb1;
    #pragma unroll
    for (int d = 0; d < DIM; ++d) {
        acca[d] = fmaf(ea0, k[0][d], acca[d]);
        accb[d] = fmaf(eb0, k[0][d], accb[d]);
        acca[d] = fmaf(ea1, k[1][d], acca[d]);
        accb[d] = fmaf(eb1, k[1][d], accb[d]);
    }
}

template <int SL>
__global__ __launch_bounds__(T1, 4) void attn_partial_fb(
    const float* __restrict__ x, float* __restrict__ ws)
{
    constexpr int KPW = BTOT / SL / WAVES;
    __shared__ float rbuf[WAVES][QPB][13];

    const int bx = blockIdx.x;
    const int qg = bx / (NN * SL);
    const int r  = bx % (NN * SL);
    const int n  = r / SL;
    const int gc = r % SL;
    const int w  = __builtin_amdgcn_readfirstlane(threadIdx.x >> 6);
    const int j  = threadIdx.x & 63;

    float qa[DIM], qb[DIM];
    {
        const float* pa = x + (qg * QPB + j) * ROW + n * DIM;
        const float* pb = pa + 64 * ROW;
        #pragma unroll
        for (int d = 0; d < DIM; d += 2) {
            float2 ta = *(const float2*)(pa + d);
            float2 tb = *(const float2*)(pb + d);
            qa[d] = ta.x * LOG2E; qa[d + 1] = ta.y * LOG2E;
            qb[d] = tb.x * LOG2E; qb[d + 1] = tb.y * LOG2E;
        }
    }

    float la = 0.f, lb = 0.f;
    float acca[DIM], accb[DIM];
    #pragma unroll
    for (int d = 0; d < DIM; ++d) { acca[d] = 0.f; accb[d] = 0.f; }

    const int kbase = gc * (BTOT / SL) + w * KPW;
    const float* kp = x + (size_t)kbase * ROW + n * DIM;

    float kA[2][DIM], kB[2][DIM];
    load2fb(kp, kA);
    for (int kk = 0; kk < KPW - 4; kk += 4) {
        load2fb(kp + 2 * ROW, kB);
        compute2fb(kA, qa, qb, acca, accb, la, lb);
        load2fb(kp + 4 * ROW, kA);
        compute2fb(kB, qa, qb, acca, accb, la, lb);
        kp += 4 * ROW;
    }
    load2fb(kp + 2 * ROW, kB);
    compute2fb(kA, qa, qb, acca, accb, la, lb);
    compute2fb(kB, qa, qb, acca, accb, la, lb);

    #pragma unroll
    for (int d = 0; d < DIM; ++d) {
        rbuf[w][j][d]      = acca[d];
        rbuf[w][j + 64][d] = accb[d];
    }
    rbuf[w][j][DIM]      = la;
    rbuf[w][j + 64][DIM] = lb;
    __syncthreads();

    for (int t = threadIdx.x; t < (DIM + 1) * QPB; t += T1) {
        int d  = t >> 7;
        int jj = t & 127;
        float s = rbuf[0][jj][d] + rbuf[1][jj][d] + rbuf[2][jj][d] + rbuf[3][jj][d];
        ws[((size_t)(n * SL + gc) * BTOT + qg * QPB + jj) * 12 + d] = s;
    }
}

template <int SL>
__global__ __launch_bounds__(192) void finalize_fb(
    const float* __restrict__ ws, const float* __restrict__ A,
    const float* __restrict__ W, const float* __restrict__ bn_g,
    const float* __restrict__ bn_b, const float* __restrict__ bn_m,
    const float* __restrict__ bn_v, float* __restrict__ out)
{
    __shared__ float ubuf[64][NN][13];
    const int tl = threadIdx.x;
    const int ql = tl & 63;
    const int n  = tl >> 6;
    const int q  = blockIdx.x * 64 + ql;

    float a[12];
    #pragma unroll
    for (int d = 0; d < 12; ++d) a[d] = 0.f;
    #pragma unroll
    for (int sl = 0; sl < SL; ++sl) {
        const float* p = ws + ((size_t)(n * SL + sl) * BTOT + q) * 12;
        float4 v0 = *(const float4*)p;
        float4 v1 = *(const float4*)(p + 4);
        float4 v2 = *(const float4*)(p + 8);
        a[0] += v0.x; a[1] += v0.y; a[2]  += v0.z; a[3]  += v0.w;
        a[4] += v1.x; a[5] += v1.y; a[6]  += v1.z; a[7]  += v1.w;
        a[8] += v2.x; a[9] += v2.y; a[10] += v2.z;
    }
    float inv = 1.0f / a[10];
    float sc = bn_g[n] * rsqrtf(bn_v[n] + EPS);
    float sh = bn_b[n] - bn_m[n] * sc;
    float cw = 0.125f * (((n == 0) ? 0.f : 1.f) + A[n] +
                         ((n == 1) ? 0.f : 1.f) + A[NN + n]);
    #pragma unroll
    for (int d = 0; d < DIM; ++d)
        ubuf[ql][n][d] = cw * (a[d] * inv * sc + sh);
    __syncthreads();

    if (tl < 64) {
        float u[DIM];
        #pragma unroll
        for (int d = 0; d < DIM; ++d)
            u[d] = ubuf[ql][0][d] + ubuf[ql][1][d] + ubuf[ql][2][d];
        #pragma unroll
        for (int dout = 0; dout < DIM; ++dout) {
            float o = 0.f;
            #pragma unroll
            for (int e = 0; e < DIM; ++e) o = fmaf(u[e], W[e * DIM + dout], o);
            out[q * DIM + dout] = o;
        }
    }
}

// ------------------------------- launch ------------------------------------
extern "C" void kernel_launch(void* const* d_in, const int* in_sizes, int n_in,
                              void* d_out, int out_size, void* d_ws, size_t ws_size,
                              hipStream_t stream) {
    const float* x  = (const float*)d_in[0];
    const float* A  = (const float*)d_in[1];
    const float* W  = (const float*)d_in[2];
    const float* g  = (const float*)d_in[3];
    const float* be = (const float*)d_in[4];
    const float* mu = (const float*)d_in[5];
    const float* va = (const float*)d_in[6];
    float* out = (float*)d_out;

    const size_t FR_DW  = (size_t)NN * NTILE * 4 * 256;     // 393216 dwords
    const size_t PWS_DW = (size_t)NN * NKQ * BTOT * PSTR;   // 1179648 dwords
    const size_t needM  = (FR_DW + PWS_DW) * 4;             // ~6.3 MB

    if (ws_size >= needM) {
        unsigned* fr = (unsigned*)d_ws;
        float* pws   = (float*)d_ws + FR_DW;
        hipLaunchKernelGGL(prep_frags, dim3(NN * NTILE), dim3(256), 0, stream, x, fr);
        hipLaunchKernelGGL(attn_mfma, dim3((BTOT/128) * NN * NKQ), dim3(256), 0, stream,
                           fr, pws);
        hipLaunchKernelGGL(finalize2, dim3(BTOT / QB2), dim3(QB2 * NN * 8), 0, stream,
                           pws, A, W, g, be, mu, va, out);
    } else {
        float* ws = (float*)d_ws;
        auto need = [](int SL) { return (size_t)NN * SL * BTOT * 12 * sizeof(float); };
        if (ws_size >= need(16)) {
            hipLaunchKernelGGL((attn_partial_fb<16>), dim3(NQG * NN * 16), dim3(T1), 0, stream, x, ws);
            hipLaunchKernelGGL((finalize_fb<16>), dim3(BTOT / 64), dim3(192), 0, stream,
                               ws, A, W, g, be, mu, va, out);
        } else if (ws_size >= need(4)) {
            hipLaunchKernelGGL((attn_partial_fb<4>),  dim3(NQG * NN * 4),  dim3(T1), 0, stream, x, ws);
            hipLaunchKernelGGL((finalize_fb<4>),  dim3(BTOT / 64), dim3(192), 0, stream,
                               ws, A, W, g, be, mu, va, out);
        } else {
            hipLaunchKernelGGL((attn_partial_fb<1>),  dim3(NQG * NN * 1),  dim3(T1), 0, stream, x, ws);
            hipLaunchKernelGGL((finalize_fb<1>),  dim3(BTOT / 64), dim3(192), 0, stream,
                               ws, A, W, g, be, mu, va, out);
        }
    }
}